// Round 5
// baseline (54.325 us; speedup 1.0000x reference)
//
#include <hip/hip_runtime.h>
#include <hip/hip_bf16.h>
#include <stdint.h>

// KANLayer as GEMM: out[8192,512] = A[8192,1536]@W[1536,512] + bias, bf16 MFMA, fp32 accum.
// K-order: 16 groups of 96; group g covers i in [g*32,g*32+32) x p in {0,1,2} (chunk ks = g*3+p).
// A-fragments computed IN-REGISTER from x (running powers + hw bf16 cvt); only W goes through LDS.
// GEMM: BM=128, BN=64, 4 waves (wr=wid>>1, wc=wid&1), wave-tile 64x32 (m=4,n=2).
// 3-deep B LDS pipeline with stage-ahead-2 (post-barrier issue), x prefetch-ahead-1 in named regs,
// steady counted vmcnt(11), one s_barrier per group.

static constexpr int ON_ = 512;

typedef __bf16 bf16x8 __attribute__((ext_vector_type(8)));
typedef float  f32x4  __attribute__((ext_vector_type(4)));

__device__ __forceinline__ unsigned int f2bf(float f) {
    unsigned int u = __float_as_uint(f);
    return ((u + 0x7FFFu + ((u >> 16) & 1u)) >> 16);   // RNE bf16, finite inputs
}

__device__ __forceinline__ float4 mul4(float4 a, float4 b) {
    return make_float4(a.x * b.x, a.y * b.y, a.z * b.z, a.w * b.w);
}

__device__ __forceinline__ void gld_lds16(const void* g, void* l) {
    __builtin_amdgcn_global_load_lds(
        (const __attribute__((address_space(1))) unsigned int*)(uintptr_t)g,
        (__attribute__((address_space(3))) unsigned int*)(unsigned int)(uintptr_t)l,
        16, 0, 0);
}

// ---- pack B (blocks 0..127) + bias (blocks 128..135).
// Chunk (cb, ks=g*3+p) at Bpk[(cb*48+ks)*1024]: lane l holds W[k][cb*16+(l&15)], k-in-chunk=(l>>4)*8+j.
__global__ __launch_bounds__(256) void pack_B_bias(const float* __restrict__ edge_w, const float* __restrict__ comb_w,
                                                   const float* __restrict__ edge_b,
                                                   uint4* __restrict__ Bpk, float* __restrict__ bias) {
    if (blockIdx.x < 128) {
        int id = blockIdx.x * 256 + threadIdx.x;
        int l  = id & 63;
        int t  = id >> 6;          // 0..511
        int g  = t & 15;
        int cb = t >> 4;           // 0..31
        int o  = cb * 16 + (l & 15);
        int i0 = g * 32 + ((l >> 4) << 3);
        unsigned int w[3][4];
#pragma unroll
        for (int j = 0; j < 4; ++j) {
            int ia = i0 + 2 * j, ic = ia + 1;
            float ca = comb_w[(size_t)ia * ON_ + o];
            float cc = comb_w[(size_t)ic * ON_ + o];
            const float* ea = edge_w + ((size_t)ia * ON_ + o) * 3;
            const float* ec = edge_w + ((size_t)ic * ON_ + o) * 3;
#pragma unroll
            for (int p = 0; p < 3; ++p)
                w[p][j] = f2bf(ea[p] * ca) | (f2bf(ec[p] * cc) << 16);
        }
        size_t base = ((size_t)cb * 48 + g * 3) * 64 + l;
        Bpk[base]       = make_uint4(w[0][0], w[0][1], w[0][2], w[0][3]);
        Bpk[base + 64]  = make_uint4(w[1][0], w[1][1], w[1][2], w[1][3]);
        Bpk[base + 128] = make_uint4(w[2][0], w[2][1], w[2][2], w[2][3]);
    } else {
        __shared__ float red[4][64];
        int bo = blockIdx.x - 128;          // 0..7, 64 o's each
        int tt = threadIdx.x;
        int o  = bo * 64 + (tt & 63);
        int iseg = tt >> 6;
        float s = 0.f;
        int ib = iseg * 128;
#pragma unroll 4
        for (int i = ib; i < ib + 128; ++i)
            s += comb_w[(size_t)i * ON_ + o] * edge_b[(size_t)i * ON_ + o];
        red[iseg][tt & 63] = s;
        __syncthreads();
        if (tt < 64)
            bias[bo * 64 + tt] = red[0][tt] + red[1][tt] + red[2][tt] + red[3][tt];
    }
}

// 8 f32 (two float4) -> bf16x8 via hw cvt (pairs into v_cvt_pk_bf16_f32)
#define CVT8(D, LO, HI) do {                                                      \
    D = (bf16x8){ (__bf16)(LO).x, (__bf16)(LO).y, (__bf16)(LO).z, (__bf16)(LO).w, \
                  (__bf16)(HI).x, (__bf16)(HI).y, (__bf16)(HI).z, (__bf16)(HI).w }; \
} while (0)

// one B-fragment (ds_read_b128 at imm offset) feeding 4 MFMAs (m=0..3)
#define MFMA8(A0, A1, A2, A3, BOFF, NI) do {                                          \
    bf16x8 b_ = *(const bf16x8*)(bp_ + (BOFF));                                       \
    acc[0][NI] = __builtin_amdgcn_mfma_f32_16x16x32_bf16(A0, b_, acc[0][NI], 0, 0, 0); \
    acc[1][NI] = __builtin_amdgcn_mfma_f32_16x16x32_bf16(A1, b_, acc[1][NI], 0, 0, 0); \
    acc[2][NI] = __builtin_amdgcn_mfma_f32_16x16x32_bf16(A2, b_, acc[2][NI], 0, 0, 0); \
    acc[3][NI] = __builtin_amdgcn_mfma_f32_16x16x32_bf16(A3, b_, acc[3][NI], 0, 0, 0); \
} while (0)

// One group-step. C*/N* are NAMED float4 registers (all indices compile-time).
// Pre-barrier: issue x(G+1) [8 VMEM]; wait; barrier; post-barrier: issue B(G+2) [3 VMEM]; compute.
#define STEP(G, C0,C1,C2,C3,C4,C5,C6,C7, N0,N1,N2,N3,N4,N5,N6,N7, WAITS) do {     \
    if ((G) + 1 < 16) {                                                           \
        const float* xr0_ = xg0 + ((G) + 1) * 32;                                 \
        const float* xr1_ = xg1 + ((G) + 1) * 32;                                 \
        const float* xr2_ = xg2 + ((G) + 1) * 32;                                 \
        const float* xr3_ = xg3 + ((G) + 1) * 32;                                 \
        N0 = *(const float4*)(xr0_); N1 = *(const float4*)(xr0_ + 4);             \
        N2 = *(const float4*)(xr1_); N3 = *(const float4*)(xr1_ + 4);             \
        N4 = *(const float4*)(xr2_); N5 = *(const float4*)(xr2_ + 4);             \
        N6 = *(const float4*)(xr3_); N7 = *(const float4*)(xr3_ + 4);             \
    }                                                                             \
    asm volatile("s_waitcnt " WAITS ::: "memory");                                \
    __builtin_amdgcn_s_barrier();                                                 \
    if ((G) + 2 < 16) {                                                           \
        const char* gs_ = gb + (size_t)((G) + 2) * 3072;                          \
        char* dl_ = (char*)lds + so + (wid << 10);                                \
        gld_lds16(gs_,        dl_);                                               \
        gld_lds16(gs_ + 1024, dl_ + 4096);                                        \
        gld_lds16(gs_ + 2048, dl_ + 8192);                                        \
    }                                                                             \
    {                                                                             \
        const char* bp_ = (const char*)lds + co + (wc << 11) + (l << 4);          \
        float4 t0=C0,t1=C1,t2=C2,t3=C3,t4=C4,t5=C5,t6=C6,t7=C7;                   \
        bf16x8 af0_, af1_, af2_, af3_;                                            \
        CVT8(af0_, t0, t1); CVT8(af1_, t2, t3);                                   \
        CVT8(af2_, t4, t5); CVT8(af3_, t6, t7);                                   \
        MFMA8(af0_, af1_, af2_, af3_, 0,    0);                                   \
        MFMA8(af0_, af1_, af2_, af3_, 1024, 1);                                   \
        t0=mul4(t0,C0); t1=mul4(t1,C1); t2=mul4(t2,C2); t3=mul4(t3,C3);           \
        t4=mul4(t4,C4); t5=mul4(t5,C5); t6=mul4(t6,C6); t7=mul4(t7,C7);           \
        CVT8(af0_, t0, t1); CVT8(af1_, t2, t3);                                   \
        CVT8(af2_, t4, t5); CVT8(af3_, t6, t7);                                   \
        MFMA8(af0_, af1_, af2_, af3_, 4096, 0);                                   \
        MFMA8(af0_, af1_, af2_, af3_, 5120, 1);                                   \
        t0=mul4(t0,C0); t1=mul4(t1,C1); t2=mul4(t2,C2); t3=mul4(t3,C3);           \
        t4=mul4(t4,C4); t5=mul4(t5,C5); t6=mul4(t6,C6); t7=mul4(t7,C7);           \
        CVT8(af0_, t0, t1); CVT8(af1_, t2, t3);                                   \
        CVT8(af2_, t4, t5); CVT8(af3_, t6, t7);                                   \
        MFMA8(af0_, af1_, af2_, af3_, 8192, 0);                                   \
        MFMA8(af0_, af1_, af2_, af3_, 9216, 1);                                   \
    }                                                                             \
    co = (co == 24576) ? 0 : co + 12288;                                          \
    so = (so == 24576) ? 0 : so + 12288;                                          \
} while (0)

__global__ __launch_bounds__(256, 2) void gemm_fused(const float* __restrict__ x,
                                                     const char* __restrict__ Bpk,
                                                     const float* __restrict__ bias,
                                                     float* __restrict__ out) {
    __shared__ char lds[36864];   // 3 bufs x 12KB; buf: [p 0..2 (4KB)][cb_local 0..3 (1KB)][lane][16B]
    const int tid = threadIdx.x;
    const int l   = tid & 63;
    const int wid = tid >> 6;
    const int wr  = wid >> 1, wc = wid & 1;

    // bijective XCD swizzle (512 % 8 == 0): XCD owns contiguous bx range -> x slice L2-resident
    int d  = blockIdx.x;
    int w  = (d & 7) * 64 + (d >> 3);
    int bx = w >> 3, by = w & 7;

    const char* gb = Bpk + ((size_t)(by * 4 + wid) * 48) * 1024 + (l << 4);
    // lane l, sub-tile m: row = bx*128 + wr*64 + m*16 + (l&15); cols (l>>4)*8.. within 32-wide i-chunk
    const float* xg0 = x + (size_t)(bx * 128 + wr * 64 + (l & 15)) * 512 + ((l >> 4) << 3);
    const float* xg1 = xg0 + 16 * 512;
    const float* xg2 = xg0 + 32 * 512;
    const float* xg3 = xg0 + 48 * 512;

    f32x4 acc[4][2] = {};                      // [m][n], indices compile-time
    float4 xA0, xA1, xA2, xA3, xA4, xA5, xA6, xA7;
    float4 xB0, xB1, xB2, xB3, xB4, xB5, xB6, xB7;

    // prologue: x(0) -> A regs [8]; stage B(0)->buf0, B(1)->buf1 [6]
    xA0 = *(const float4*)(xg0); xA1 = *(const float4*)(xg0 + 4);
    xA2 = *(const float4*)(xg1); xA3 = *(const float4*)(xg1 + 4);
    xA4 = *(const float4*)(xg2); xA5 = *(const float4*)(xg2 + 4);
    xA6 = *(const float4*)(xg3); xA7 = *(const float4*)(xg3 + 4);
    {
        char* dl = (char*)lds + (wid << 10);
        gld_lds16(gb,        dl);
        gld_lds16(gb + 1024, dl + 4096);
        gld_lds16(gb + 2048, dl + 8192);
        gld_lds16(gb + 3072, dl + 12288);
        gld_lds16(gb + 4096, dl + 12288 + 4096);
        gld_lds16(gb + 5120, dl + 12288 + 8192);
    }

    int co = 0;        // compute buffer offset: G%3 * 12288
    int so = 24576;    // stage buffer offset: (G+2)%3 * 12288

    for (int gp = 0; gp < 7; ++gp) {           // G = 0..13
        STEP(2 * gp,     xA0,xA1,xA2,xA3,xA4,xA5,xA6,xA7, xB0,xB1,xB2,xB3,xB4,xB5,xB6,xB7, "vmcnt(11)");
        STEP(2 * gp + 1, xB0,xB1,xB2,xB3,xB4,xB5,xB6,xB7, xA0,xA1,xA2,xA3,xA4,xA5,xA6,xA7, "vmcnt(11)");
    }
    STEP(14, xA0,xA1,xA2,xA3,xA4,xA5,xA6,xA7, xB0,xB1,xB2,xB3,xB4,xB5,xB6,xB7, "vmcnt(11)");
    STEP(15, xB0,xB1,xB2,xB3,xB4,xB5,xB6,xB7, xA0,xA1,xA2,xA3,xA4,xA5,xA6,xA7, "vmcnt(0)");

    // epilogue: C/D layout col=lane&15, row=(lane>>4)*4+reg
    int lr = l >> 4, lc = l & 15;
#pragma unroll
    for (int n = 0; n < 2; ++n) {
        int o = (by << 6) + (wc << 5) + (n << 4) + lc;
        float bv = bias[o];
#pragma unroll
        for (int m = 0; m < 4; ++m) {
            int r0 = (bx << 7) + (wr << 6) + (m << 4) + (lr << 2);
#pragma unroll
            for (int j = 0; j < 4; ++j)
                out[(size_t)(r0 + j) * ON_ + o] = acc[m][n][j] + bv;
        }
    }
}

extern "C" void kernel_launch(void* const* d_in, const int* in_sizes, int n_in,
                              void* d_out, int out_size, void* d_ws, size_t ws_size,
                              hipStream_t stream) {
    const float* x      = (const float*)d_in[0];
    const float* edge_w = (const float*)d_in[1];
    const float* edge_b = (const float*)d_in[2];
    const float* comb_w = (const float*)d_in[3];
    float* out = (float*)d_out;

    char* ws = (char*)d_ws;
    char* Bpk   = ws;                        // 1536*512*2 = 1,572,864 B
    float* bias = (float*)(ws + 1572864);    // 512*4 B

    hipLaunchKernelGGL(pack_B_bias, dim3(128 + 8), dim3(256), 0, stream, edge_w, comb_w, edge_b, (uint4*)Bpk, bias);
    hipLaunchKernelGGL(gemm_fused, dim3(512), dim3(256), 0, stream, x, Bpk, bias, out);
}

// Round 6
// 40.427 us; speedup vs baseline: 1.3438x; 1.3438x over previous
//
#include <hip/hip_runtime.h>
#include <hip/hip_bf16.h>
#include <stdint.h>

// KANLayer as GEMM: out[8192,512] = A[8192,1536]@W[1536,512] + bias, bf16 MFMA, fp32 accum.
// A[b, k(g,p)] = x[b, g*32+ic]^(p+1).  ALL GEMM loads are coalesced chunk loads:
//   Xpk[rb][g]: 1KB chunk, lane l = bf16 x[rb*16+(l&15)][g*32+(l>>4)*8 .. +7]   (8 MB)
//   Bpk[cb][g][p]: 1KB chunk, lane l = bf16 W[...][cb*16+(l&15)]                (1.5 MB)
// x^2, x^3 built in-register from bf16 x (shift-extract f32, mul, cvt_pk back).
// GEMM has NO LDS and NO barriers: independent waves, depth-1 prefetch, counted vmcnt.

static constexpr int ON_ = 512;

typedef __bf16 bf16x8 __attribute__((ext_vector_type(8)));
typedef float  f32x4  __attribute__((ext_vector_type(4)));

__device__ __forceinline__ unsigned int f2bf(float f) {
    unsigned int u = __float_as_uint(f);
    return ((u + 0x7FFFu + ((u >> 16) & 1u)) >> 16);   // RNE bf16, finite inputs
}

// ---- fused pack: blocks [0,2048) pack x -> Xpk ; [2048,2176) pack B ; [2176,2184) bias
__global__ __launch_bounds__(256) void pack_all(const float* __restrict__ x,
                                                const float* __restrict__ edge_w,
                                                const float* __restrict__ comb_w,
                                                const float* __restrict__ edge_b,
                                                uint4* __restrict__ Xpk,
                                                uint4* __restrict__ Bpk,
                                                float* __restrict__ bias) {
    int bb = blockIdx.x;
    if (bb < 2048) {
        int id = bb * 256 + threadIdx.x;
        int l  = id & 63;
        int w  = id >> 6;              // 0..8191: rb = w>>4, g = w&15
        int g  = w & 15;
        int rb = w >> 4;
        int r  = rb * 16 + (l & 15);
        int c  = g * 32 + ((l >> 4) << 3);
        const float4* xp = (const float4*)(x + (size_t)r * 512 + c);
        float4 v0 = xp[0], v1 = xp[1];
        uint4 o;
        o.x = f2bf(v0.x) | (f2bf(v0.y) << 16);
        o.y = f2bf(v0.z) | (f2bf(v0.w) << 16);
        o.z = f2bf(v1.x) | (f2bf(v1.y) << 16);
        o.w = f2bf(v1.z) | (f2bf(v1.w) << 16);
        Xpk[(size_t)w * 64 + l] = o;   // coalesced 1KB store per wave
    } else if (bb < 2176) {
        int id = (bb - 2048) * 256 + threadIdx.x;
        int l  = id & 63;
        int t  = id >> 6;              // 0..511
        int g  = t & 15;
        int cb = t >> 4;               // 0..31
        int o  = cb * 16 + (l & 15);
        int i0 = g * 32 + ((l >> 4) << 3);
        unsigned int w[3][4];
#pragma unroll
        for (int j = 0; j < 4; ++j) {
            int ia = i0 + 2 * j, ic = ia + 1;
            float ca = comb_w[(size_t)ia * ON_ + o];
            float cc = comb_w[(size_t)ic * ON_ + o];
            const float* ea = edge_w + ((size_t)ia * ON_ + o) * 3;
            const float* ec = edge_w + ((size_t)ic * ON_ + o) * 3;
#pragma unroll
            for (int p = 0; p < 3; ++p)
                w[p][j] = f2bf(ea[p] * ca) | (f2bf(ec[p] * cc) << 16);
        }
        size_t base = ((size_t)cb * 48 + g * 3) * 64 + l;
        Bpk[base]       = make_uint4(w[0][0], w[0][1], w[0][2], w[0][3]);
        Bpk[base + 64]  = make_uint4(w[1][0], w[1][1], w[1][2], w[1][3]);
        Bpk[base + 128] = make_uint4(w[2][0], w[2][1], w[2][2], w[2][3]);
    } else {
        __shared__ float red[4][64];
        int bo = bb - 2176;            // 0..7, 64 o's each
        int tt = threadIdx.x;
        int o  = bo * 64 + (tt & 63);
        int iseg = tt >> 6;
        float s = 0.f;
        int ib = iseg * 128;
#pragma unroll 4
        for (int i = ib; i < ib + 128; ++i)
            s += comb_w[(size_t)i * ON_ + o] * edge_b[(size_t)i * ON_ + o];
        red[iseg][tt & 63] = s;
        __syncthreads();
        if (tt < 64)
            bias[bo * 64 + tt] = red[0][tt] + red[1][tt] + red[2][tt] + red[3][tt];
    }
}

// powers + 6 MFMAs for one m-strip. a1 = raw bf16 x; a2/a3 from shift-extracted f32.
#define PM(CAm, MI, CB0_, CB1_, CB2_, CB3_, CB4_, CB5_) do {                           \
    bf16x8 a1_ = __builtin_bit_cast(bf16x8, (CAm));                                    \
    float e0_ = __uint_as_float((CAm).x << 16), e1_ = __uint_as_float((CAm).x & 0xffff0000u); \
    float e2_ = __uint_as_float((CAm).y << 16), e3_ = __uint_as_float((CAm).y & 0xffff0000u); \
    float e4_ = __uint_as_float((CAm).z << 16), e5_ = __uint_as_float((CAm).z & 0xffff0000u); \
    float e6_ = __uint_as_float((CAm).w << 16), e7_ = __uint_as_float((CAm).w & 0xffff0000u); \
    float q0_ = e0_*e0_, q1_ = e1_*e1_, q2_ = e2_*e2_, q3_ = e3_*e3_;                  \
    float q4_ = e4_*e4_, q5_ = e5_*e5_, q6_ = e6_*e6_, q7_ = e7_*e7_;                  \
    bf16x8 a2_ = (bf16x8){ (__bf16)q0_, (__bf16)q1_, (__bf16)q2_, (__bf16)q3_,         \
                           (__bf16)q4_, (__bf16)q5_, (__bf16)q6_, (__bf16)q7_ };       \
    bf16x8 a3_ = (bf16x8){ (__bf16)(q0_*e0_), (__bf16)(q1_*e1_), (__bf16)(q2_*e2_), (__bf16)(q3_*e3_), \
                           (__bf16)(q4_*e4_), (__bf16)(q5_*e5_), (__bf16)(q6_*e6_), (__bf16)(q7_*e7_) }; \
    acc[MI][0] = __builtin_amdgcn_mfma_f32_16x16x32_bf16(a1_, __builtin_bit_cast(bf16x8, CB0_), acc[MI][0], 0, 0, 0); \
    acc[MI][1] = __builtin_amdgcn_mfma_f32_16x16x32_bf16(a1_, __builtin_bit_cast(bf16x8, CB3_), acc[MI][1], 0, 0, 0); \
    acc[MI][0] = __builtin_amdgcn_mfma_f32_16x16x32_bf16(a2_, __builtin_bit_cast(bf16x8, CB1_), acc[MI][0], 0, 0, 0); \
    acc[MI][1] = __builtin_amdgcn_mfma_f32_16x16x32_bf16(a2_, __builtin_bit_cast(bf16x8, CB4_), acc[MI][1], 0, 0, 0); \
    acc[MI][0] = __builtin_amdgcn_mfma_f32_16x16x32_bf16(a3_, __builtin_bit_cast(bf16x8, CB2_), acc[MI][0], 0, 0, 0); \
    acc[MI][1] = __builtin_amdgcn_mfma_f32_16x16x32_bf16(a3_, __builtin_bit_cast(bf16x8, CB5_), acc[MI][1], 0, 0, 0); \
} while (0)

// One group-step: prefetch next group's 10 chunks into N*, wait current drained, compute C*.
// All frag regs NAMED (compile-time) -> no scratch. 10 VMEM/step -> steady vmcnt(10).
#define STEP(PREF, CA0,CA1,CA2,CA3, CB0,CB1,CB2,CB3,CB4,CB5,                           \
                   NA0,NA1,NA2,NA3, NB0,NB1,NB2,NB3,NB4,NB5, WAITS) do {               \
    if (PREF) {                                                                        \
        NA0 = *(const uint4*)(pa0); NA1 = *(const uint4*)(pa1);                        \
        NA2 = *(const uint4*)(pa2); NA3 = *(const uint4*)(pa3);                        \
        NB0 = *(const uint4*)(pb0);        NB1 = *(const uint4*)(pb0 + 1024);          \
        NB2 = *(const uint4*)(pb0 + 2048); NB3 = *(const uint4*)(pb1);                 \
        NB4 = *(const uint4*)(pb1 + 1024); NB5 = *(const uint4*)(pb1 + 2048);          \
        pa0 += 1024; pa1 += 1024; pa2 += 1024; pa3 += 1024;                            \
        pb0 += 3072; pb1 += 3072;                                                      \
    }                                                                                  \
    asm volatile("s_waitcnt " WAITS ::: "memory");                                     \
    PM(CA0, 0, CB0, CB1, CB2, CB3, CB4, CB5);                                          \
    PM(CA1, 1, CB0, CB1, CB2, CB3, CB4, CB5);                                          \
    PM(CA2, 2, CB0, CB1, CB2, CB3, CB4, CB5);                                          \
    PM(CA3, 3, CB0, CB1, CB2, CB3, CB4, CB5);                                          \
} while (0)

// GEMM: BM=128, BN=64, 4 waves 2x2 (wr,wc), wave-tile 64x32. No LDS, no barriers.
__global__ __launch_bounds__(256, 2) void gemm_fused(const char* __restrict__ Xpk,
                                                     const char* __restrict__ Bpk,
                                                     const float* __restrict__ bias,
                                                     float* __restrict__ out) {
    const int tid = threadIdx.x;
    const int l   = tid & 63;
    const int wid = tid >> 6;
    const int wr  = wid >> 1, wc = wid & 1;

    // bijective XCD swizzle (512 % 8 == 0)
    int d  = blockIdx.x;
    int w  = (d & 7) * 64 + (d >> 3);
    int bx = w >> 3, by = w & 7;

    // running per-lane chunk pointers (advance per group)
    const char* pa0 = Xpk + ((size_t)(bx * 8 + wr * 4) * 16) * 1024 + (l << 4);
    const char* pa1 = pa0 + 16 * 1024;
    const char* pa2 = pa0 + 32 * 1024;
    const char* pa3 = pa0 + 48 * 1024;
    const char* pb0 = Bpk + ((size_t)(by * 4 + wc * 2) * 48) * 1024 + (l << 4);
    const char* pb1 = pb0 + 48 * 1024;

    f32x4 acc[4][2] = {};
    uint4 cA0, cA1, cA2, cA3, cB0, cB1, cB2, cB3, cB4, cB5;
    uint4 nA0, nA1, nA2, nA3, nB0, nB1, nB2, nB3, nB4, nB5;

    // prologue: load group 0 (10 chunks)
    cA0 = *(const uint4*)(pa0); cA1 = *(const uint4*)(pa1);
    cA2 = *(const uint4*)(pa2); cA3 = *(const uint4*)(pa3);
    cB0 = *(const uint4*)(pb0);        cB1 = *(const uint4*)(pb0 + 1024);
    cB2 = *(const uint4*)(pb0 + 2048); cB3 = *(const uint4*)(pb1);
    cB4 = *(const uint4*)(pb1 + 1024); cB5 = *(const uint4*)(pb1 + 2048);
    pa0 += 1024; pa1 += 1024; pa2 += 1024; pa3 += 1024;
    pb0 += 3072; pb1 += 3072;

    for (int gp = 0; gp < 7; ++gp) {   // groups 0..13 as ping-pong pairs
        STEP(true, cA0,cA1,cA2,cA3, cB0,cB1,cB2,cB3,cB4,cB5,
                   nA0,nA1,nA2,nA3, nB0,nB1,nB2,nB3,nB4,nB5, "vmcnt(10)");
        STEP(true, nA0,nA1,nA2,nA3, nB0,nB1,nB2,nB3,nB4,nB5,
                   cA0,cA1,cA2,cA3, cB0,cB1,cB2,cB3,cB4,cB5, "vmcnt(10)");
    }
    STEP(true,  cA0,cA1,cA2,cA3, cB0,cB1,cB2,cB3,cB4,cB5,
                nA0,nA1,nA2,nA3, nB0,nB1,nB2,nB3,nB4,nB5, "vmcnt(10)");   // g=14
    STEP(false, nA0,nA1,nA2,nA3, nB0,nB1,nB2,nB3,nB4,nB5,
                cA0,cA1,cA2,cA3, cB0,cB1,cB2,cB3,cB4,cB5, "vmcnt(0)");    // g=15

    // epilogue: C/D layout col=lane&15, row=(lane>>4)*4+reg
    int lr = l >> 4, lc = l & 15;
#pragma unroll
    for (int n = 0; n < 2; ++n) {
        int o = (by << 6) + (wc << 5) + (n << 4) + lc;
        float bv = bias[o];
#pragma unroll
        for (int m = 0; m < 4; ++m) {
            int r0 = (bx << 7) + (wr << 6) + (m << 4) + (lr << 2);
#pragma unroll
            for (int j = 0; j < 4; ++j)
                out[(size_t)(r0 + j) * ON_ + o] = acc[m][n][j] + bv;
        }
    }
}

extern "C" void kernel_launch(void* const* d_in, const int* in_sizes, int n_in,
                              void* d_out, int out_size, void* d_ws, size_t ws_size,
                              hipStream_t stream) {
    const float* x      = (const float*)d_in[0];
    const float* edge_w = (const float*)d_in[1];
    const float* edge_b = (const float*)d_in[2];
    const float* comb_w = (const float*)d_in[3];
    float* out = (float*)d_out;

    char* ws = (char*)d_ws;
    char* Xpk   = ws;                               // 8192*512*2   = 8,388,608 B
    char* Bpk   = ws + 8388608;                     // 1536*512*2   = 1,572,864 B
    float* bias = (float*)(ws + 8388608 + 1572864); // 512*4 B

    hipLaunchKernelGGL(pack_all, dim3(2048 + 128 + 8), dim3(256), 0, stream,
                       x, edge_w, comb_w, edge_b, (uint4*)Xpk, (uint4*)Bpk, bias);
    hipLaunchKernelGGL(gemm_fused, dim3(512), dim3(256), 0, stream, Xpk, Bpk, bias, out);
}

// Round 7
// 40.264 us; speedup vs baseline: 1.3492x; 1.0040x over previous
//
#include <hip/hip_runtime.h>
#include <hip/hip_bf16.h>
#include <stdint.h>

// KANLayer as GEMM: out[8192,512] = A[8192,1536]@W[1536,512] + bias, bf16 MFMA, fp32 accum.
// A[b, k(g,p)] = x[b, g*32+ic]^(p+1).  ALL GEMM loads are coalesced chunk loads:
//   Xpk[rb][g]: 1KB chunk, lane l = bf16 x[rb*16+(l&15)][g*32+(l>>4)*8 .. +7]   (8 MB)
//   Bpk[cb][g][p]: 1KB chunk, lane l = bf16 W[...][cb*16+(l&15)]                (1.5 MB)
// x^2, x^3 built in-register from bf16 x.  GEMM: no LDS, no barriers, independent waves,
// DEPTH-2 register prefetch (3 named buffer sets), steady vmcnt(20), MFMA dep-distance 8.

static constexpr int ON_ = 512;

typedef __bf16 bf16x8 __attribute__((ext_vector_type(8)));
typedef float  f32x4  __attribute__((ext_vector_type(4)));

__device__ __forceinline__ unsigned int f2bf(float f) {
    unsigned int u = __float_as_uint(f);
    return ((u + 0x7FFFu + ((u >> 16) & 1u)) >> 16);   // RNE bf16, finite inputs
}

// ---- fused pack: blocks [0,2048) pack x -> Xpk ; [2048,2176) pack B ; [2176,2184) bias
__global__ __launch_bounds__(256) void pack_all(const float* __restrict__ x,
                                                const float* __restrict__ edge_w,
                                                const float* __restrict__ comb_w,
                                                const float* __restrict__ edge_b,
                                                uint4* __restrict__ Xpk,
                                                uint4* __restrict__ Bpk,
                                                float* __restrict__ bias) {
    int bb = blockIdx.x;
    if (bb < 2048) {
        int id = bb * 256 + threadIdx.x;
        int l  = id & 63;
        int w  = id >> 6;              // 0..8191: rb = w>>4, g = w&15
        int g  = w & 15;
        int rb = w >> 4;
        int r  = rb * 16 + (l & 15);
        int c  = g * 32 + ((l >> 4) << 3);
        const float4* xp = (const float4*)(x + (size_t)r * 512 + c);
        float4 v0 = xp[0], v1 = xp[1];
        uint4 o;
        o.x = f2bf(v0.x) | (f2bf(v0.y) << 16);
        o.y = f2bf(v0.z) | (f2bf(v0.w) << 16);
        o.z = f2bf(v1.x) | (f2bf(v1.y) << 16);
        o.w = f2bf(v1.z) | (f2bf(v1.w) << 16);
        Xpk[(size_t)w * 64 + l] = o;   // coalesced 1KB store per wave
    } else if (bb < 2176) {
        int id = (bb - 2048) * 256 + threadIdx.x;
        int l  = id & 63;
        int t  = id >> 6;              // 0..511
        int g  = t & 15;
        int cb = t >> 4;               // 0..31
        int o  = cb * 16 + (l & 15);
        int i0 = g * 32 + ((l >> 4) << 3);
        unsigned int w[3][4];
#pragma unroll
        for (int j = 0; j < 4; ++j) {
            int ia = i0 + 2 * j, ic = ia + 1;
            float ca = comb_w[(size_t)ia * ON_ + o];
            float cc = comb_w[(size_t)ic * ON_ + o];
            const float* ea = edge_w + ((size_t)ia * ON_ + o) * 3;
            const float* ec = edge_w + ((size_t)ic * ON_ + o) * 3;
#pragma unroll
            for (int p = 0; p < 3; ++p)
                w[p][j] = f2bf(ea[p] * ca) | (f2bf(ec[p] * cc) << 16);
        }
        size_t base = ((size_t)cb * 48 + g * 3) * 64 + l;
        Bpk[base]       = make_uint4(w[0][0], w[0][1], w[0][2], w[0][3]);
        Bpk[base + 64]  = make_uint4(w[1][0], w[1][1], w[1][2], w[1][3]);
        Bpk[base + 128] = make_uint4(w[2][0], w[2][1], w[2][2], w[2][3]);
    } else {
        __shared__ float red[4][64];
        int bo = bb - 2176;            // 0..7, 64 o's each
        int tt = threadIdx.x;
        int o  = bo * 64 + (tt & 63);
        int iseg = tt >> 6;
        float s = 0.f;
        int ib = iseg * 128;
#pragma unroll 4
        for (int i = ib; i < ib + 128; ++i)
            s += comb_w[(size_t)i * ON_ + o] * edge_b[(size_t)i * ON_ + o];
        red[iseg][tt & 63] = s;
        __syncthreads();
        if (tt < 64)
            bias[bo * 64 + tt] = red[0][tt] + red[1][tt] + red[2][tt] + red[3][tt];
    }
}

__device__ __forceinline__ void ext_sq(const uint4 a, float* e, float* q) {
    e[0] = __uint_as_float(a.x << 16); e[1] = __uint_as_float(a.x & 0xffff0000u);
    e[2] = __uint_as_float(a.y << 16); e[3] = __uint_as_float(a.y & 0xffff0000u);
    e[4] = __uint_as_float(a.z << 16); e[5] = __uint_as_float(a.z & 0xffff0000u);
    e[6] = __uint_as_float(a.w << 16); e[7] = __uint_as_float(a.w & 0xffff0000u);
#pragma unroll
    for (int i = 0; i < 8; ++i) q[i] = e[i] * e[i];
}

#define MFMA_ROW(F0, F1, F2, F3, BN0, BN1) do {                                           \
    bf16x8 b0_ = __builtin_bit_cast(bf16x8, BN0);                                         \
    bf16x8 b1_ = __builtin_bit_cast(bf16x8, BN1);                                         \
    acc[0][0] = __builtin_amdgcn_mfma_f32_16x16x32_bf16(F0, b0_, acc[0][0], 0, 0, 0);      \
    acc[1][0] = __builtin_amdgcn_mfma_f32_16x16x32_bf16(F1, b0_, acc[1][0], 0, 0, 0);      \
    acc[2][0] = __builtin_amdgcn_mfma_f32_16x16x32_bf16(F2, b0_, acc[2][0], 0, 0, 0);      \
    acc[3][0] = __builtin_amdgcn_mfma_f32_16x16x32_bf16(F3, b0_, acc[3][0], 0, 0, 0);      \
    acc[0][1] = __builtin_amdgcn_mfma_f32_16x16x32_bf16(F0, b1_, acc[0][1], 0, 0, 0);      \
    acc[1][1] = __builtin_amdgcn_mfma_f32_16x16x32_bf16(F1, b1_, acc[1][1], 0, 0, 0);      \
    acc[2][1] = __builtin_amdgcn_mfma_f32_16x16x32_bf16(F2, b1_, acc[2][1], 0, 0, 0);      \
    acc[3][1] = __builtin_amdgcn_mfma_f32_16x16x32_bf16(F3, b1_, acc[3][1], 0, 0, 0);      \
} while (0)

// compute one group from buffer regs (A0..A3 = x chunks for m=0..3; B0..B5 = W chunks)
// order: 8 a1-MFMAs | build squares | 8 a2-MFMAs | build cubes | 8 a3-MFMAs  (dep dist 8)
#define COMP(A0, A1, A2, A3, B0, B1, B2, B3, B4, B5) do {                                  \
    bf16x8 f0_ = __builtin_bit_cast(bf16x8, A0), f1_ = __builtin_bit_cast(bf16x8, A1);     \
    bf16x8 f2_ = __builtin_bit_cast(bf16x8, A2), f3_ = __builtin_bit_cast(bf16x8, A3);     \
    MFMA_ROW(f0_, f1_, f2_, f3_, B0, B3);                                                  \
    float e0_[8], q0_[8], e1_[8], q1_[8], e2_[8], q2_[8], e3_[8], q3_[8];                  \
    ext_sq(A0, e0_, q0_); ext_sq(A1, e1_, q1_);                                            \
    ext_sq(A2, e2_, q2_); ext_sq(A3, e3_, q3_);                                            \
    bf16x8 s0_ = (bf16x8){ (__bf16)q0_[0], (__bf16)q0_[1], (__bf16)q0_[2], (__bf16)q0_[3], \
                           (__bf16)q0_[4], (__bf16)q0_[5], (__bf16)q0_[6], (__bf16)q0_[7] };\
    bf16x8 s1_ = (bf16x8){ (__bf16)q1_[0], (__bf16)q1_[1], (__bf16)q1_[2], (__bf16)q1_[3], \
                           (__bf16)q1_[4], (__bf16)q1_[5], (__bf16)q1_[6], (__bf16)q1_[7] };\
    bf16x8 s2_ = (bf16x8){ (__bf16)q2_[0], (__bf16)q2_[1], (__bf16)q2_[2], (__bf16)q2_[3], \
                           (__bf16)q2_[4], (__bf16)q2_[5], (__bf16)q2_[6], (__bf16)q2_[7] };\
    bf16x8 s3_ = (bf16x8){ (__bf16)q3_[0], (__bf16)q3_[1], (__bf16)q3_[2], (__bf16)q3_[3], \
                           (__bf16)q3_[4], (__bf16)q3_[5], (__bf16)q3_[6], (__bf16)q3_[7] };\
    MFMA_ROW(s0_, s1_, s2_, s3_, B1, B4);                                                  \
    bf16x8 c0_ = (bf16x8){ (__bf16)(q0_[0]*e0_[0]), (__bf16)(q0_[1]*e0_[1]), (__bf16)(q0_[2]*e0_[2]), (__bf16)(q0_[3]*e0_[3]), \
                           (__bf16)(q0_[4]*e0_[4]), (__bf16)(q0_[5]*e0_[5]), (__bf16)(q0_[6]*e0_[6]), (__bf16)(q0_[7]*e0_[7]) }; \
    bf16x8 c1_ = (bf16x8){ (__bf16)(q1_[0]*e1_[0]), (__bf16)(q1_[1]*e1_[1]), (__bf16)(q1_[2]*e1_[2]), (__bf16)(q1_[3]*e1_[3]), \
                           (__bf16)(q1_[4]*e1_[4]), (__bf16)(q1_[5]*e1_[5]), (__bf16)(q1_[6]*e1_[6]), (__bf16)(q1_[7]*e1_[7]) }; \
    bf16x8 c2_ = (bf16x8){ (__bf16)(q2_[0]*e2_[0]), (__bf16)(q2_[1]*e2_[1]), (__bf16)(q2_[2]*e2_[2]), (__bf16)(q2_[3]*e2_[3]), \
                           (__bf16)(q2_[4]*e2_[4]), (__bf16)(q2_[5]*e2_[5]), (__bf16)(q2_[6]*e2_[6]), (__bf16)(q2_[7]*e2_[7]) }; \
    bf16x8 c3_ = (bf16x8){ (__bf16)(q3_[0]*e3_[0]), (__bf16)(q3_[1]*e3_[1]), (__bf16)(q3_[2]*e3_[2]), (__bf16)(q3_[3]*e3_[3]), \
                           (__bf16)(q3_[4]*e3_[4]), (__bf16)(q3_[5]*e3_[5]), (__bf16)(q3_[6]*e3_[6]), (__bf16)(q3_[7]*e3_[7]) }; \
    MFMA_ROW(c0_, c1_, c2_, c3_, B2, B5);                                                  \
} while (0)

// load one group's 10 chunks into named regs; advance pointers
#define LOADG(B0, B1, B2, B3, B4, B5, B6, B7, B8, B9) do {                                 \
    B0 = *(const uint4*)(pa0); B1 = *(const uint4*)(pa1);                                  \
    B2 = *(const uint4*)(pa2); B3 = *(const uint4*)(pa3);                                  \
    B4 = *(const uint4*)(pb0);        B5 = *(const uint4*)(pb0 + 1024);                    \
    B6 = *(const uint4*)(pb0 + 2048); B7 = *(const uint4*)(pb1);                           \
    B8 = *(const uint4*)(pb1 + 1024); B9 = *(const uint4*)(pb1 + 2048);                    \
    pa0 += 1024; pa1 += 1024; pa2 += 1024; pa3 += 1024;                                    \
    pb0 += 3072; pb1 += 3072;                                                              \
} while (0)

#define WAITV(N) asm volatile("s_waitcnt vmcnt(" #N ")" ::: "memory")

// GEMM: BM=128, BN=64, 4 waves 2x2 (wr,wc), wave-tile 64x32. No LDS, no barriers.
__global__ __launch_bounds__(256, 2) void gemm_fused(const char* __restrict__ Xpk,
                                                     const char* __restrict__ Bpk,
                                                     const float* __restrict__ bias,
                                                     float* __restrict__ out) {
    const int tid = threadIdx.x;
    const int l   = tid & 63;
    const int wid = tid >> 6;
    const int wr  = wid >> 1, wc = wid & 1;

    // bijective XCD swizzle (512 % 8 == 0)
    int d  = blockIdx.x;
    int w  = (d & 7) * 64 + (d >> 3);
    int bx = w >> 3, by = w & 7;

    // running per-lane chunk pointers (advance per group)
    const char* pa0 = Xpk + ((size_t)(bx * 8 + wr * 4) * 16) * 1024 + (l << 4);
    const char* pa1 = pa0 + 16 * 1024;
    const char* pa2 = pa0 + 32 * 1024;
    const char* pa3 = pa0 + 48 * 1024;
    const char* pb0 = Bpk + ((size_t)(by * 4 + wc * 2) * 48) * 1024 + (l << 4);
    const char* pb1 = pb0 + 48 * 1024;

    f32x4 acc[4][2] = {};
    uint4 u0, u1, u2, u3, u4, u5, u6, u7, u8, u9;   // buffer set U
    uint4 v0, v1, v2, v3, v4, v5, v6, v7, v8, v9;   // buffer set V
    uint4 w0, w1, w2, w3, w4, w5, w6, w7, w8, w9;   // buffer set W

    // prologue: groups 0,1 -> U,V (20 loads in flight)
    LOADG(u0, u1, u2, u3, u4, u5, u6, u7, u8, u9);
    LOADG(v0, v1, v2, v3, v4, v5, v6, v7, v8, v9);

    // steps g=0..11: 4 triples; compute U,V,W; prefetch into W,U,V (target (g+2)%3)
#pragma unroll 1
    for (int tr = 0; tr < 4; ++tr) {
        LOADG(w0, w1, w2, w3, w4, w5, w6, w7, w8, w9);
        WAITV(20);
        COMP(u0, u1, u2, u3, u4, u5, u6, u7, u8, u9);
        LOADG(u0, u1, u2, u3, u4, u5, u6, u7, u8, u9);
        WAITV(20);
        COMP(v0, v1, v2, v3, v4, v5, v6, v7, v8, v9);
        LOADG(v0, v1, v2, v3, v4, v5, v6, v7, v8, v9);
        WAITV(20);
        COMP(w0, w1, w2, w3, w4, w5, w6, w7, w8, w9);
    }
    // g=12: compute U, prefetch g14 -> W
    LOADG(w0, w1, w2, w3, w4, w5, w6, w7, w8, w9);
    WAITV(20);
    COMP(u0, u1, u2, u3, u4, u5, u6, u7, u8, u9);
    // g=13: compute V, prefetch g15 -> U
    LOADG(u0, u1, u2, u3, u4, u5, u6, u7, u8, u9);
    WAITV(20);
    COMP(v0, v1, v2, v3, v4, v5, v6, v7, v8, v9);
    // g=14: compute W (only g15's 10 loads outstanding)
    WAITV(10);
    COMP(w0, w1, w2, w3, w4, w5, w6, w7, w8, w9);
    // g=15: compute U
    WAITV(0);
    COMP(u0, u1, u2, u3, u4, u5, u6, u7, u8, u9);

    // epilogue: C/D layout col=lane&15, row=(lane>>4)*4+reg
    int lr = l >> 4, lc = l & 15;
#pragma unroll
    for (int n = 0; n < 2; ++n) {
        int o = (by << 6) + (wc << 5) + (n << 4) + lc;
        float bv = bias[o];
#pragma unroll
        for (int m = 0; m < 4; ++m) {
            int r0 = (bx << 7) + (wr << 6) + (m << 4) + (lr << 2);
#pragma unroll
            for (int j = 0; j < 4; ++j)
                out[(size_t)(r0 + j) * ON_ + o] = acc[m][n][j] + bv;
        }
    }
}

extern "C" void kernel_launch(void* const* d_in, const int* in_sizes, int n_in,
                              void* d_out, int out_size, void* d_ws, size_t ws_size,
                              hipStream_t stream) {
    const float* x      = (const float*)d_in[0];
    const float* edge_w = (const float*)d_in[1];
    const float* edge_b = (const float*)d_in[2];
    const float* comb_w = (const float*)d_in[3];
    float* out = (float*)d_out;

    char* ws = (char*)d_ws;
    char* Xpk   = ws;                               // 8192*512*2   = 8,388,608 B
    char* Bpk   = ws + 8388608;                     // 1536*512*2   = 1,572,864 B
    float* bias = (float*)(ws + 8388608 + 1572864); // 512*4 B

    hipLaunchKernelGGL(pack_all, dim3(2048 + 128 + 8), dim3(256), 0, stream,
                       x, edge_w, comb_w, edge_b, (uint4*)Xpk, (uint4*)Bpk, bias);
    hipLaunchKernelGGL(gemm_fused, dim3(512), dim3(256), 0, stream, Xpk, Bpk, bias, out);
}